// Round 1
// baseline (86.154 us; speedup 1.0000x reference)
//
#include <hip/hip_runtime.h>

// out[j,i] = sum_k exp(-(x_k - i/512)^2 * 5000) * exp(-(y_k - j/512)^2 * 5000)
// 1024 points (8 curves x 128 steps), 512x512 fp32 output.
//
// Fused single kernel: each block computes a 64x64 output tile for a 256-wide
// K-slice. Bezier points -> LDS, factor tiles (exp) -> LDS, 4x4 fp32 micro-tile
// per thread, atomicAdd combine across the 4 K-slices.

constexpr int RES_  = 512;
constexpr int TILE  = 64;   // output tile edge
constexpr int KB    = 256;  // K range per block (1024 / KSPLIT)
constexpr int KC    = 64;   // K chunk staged in LDS

__global__ __launch_bounds__(256)
void bezier_raster(const float* __restrict__ curves, float* __restrict__ out) {
    __shared__ float xs[KB], ys[KB];
    __shared__ float ex_s[KC][TILE];   // 16 KB
    __shared__ float ey_s[KC][TILE];   // 16 KB

    const int tid   = threadIdx.x;
    const int ibase = blockIdx.x * TILE;   // output columns i
    const int jbase = blockIdx.y * TILE;   // output rows j
    const int kbase = blockIdx.z * KB;     // K slice

    // --- evaluate one Bezier sample point per thread (de Casteljau, fp32) ---
    {
        int p = kbase + tid;                       // global point index
        int c = p >> 7;                            // curve 0..7
        float t = (float)(p & 127) * (1.0f / 127.0f);
        const float* cp = curves + c * 8;          // 4 control points x (x,y)
        float p0x = cp[0], p0y = cp[1];
        float p1x = cp[2], p1y = cp[3];
        float p2x = cp[4], p2y = cp[5];
        float p3x = cp[6], p3y = cp[7];
        float a01x = p0x + (p1x - p0x) * t, a01y = p0y + (p1y - p0y) * t;
        float a12x = p1x + (p2x - p1x) * t, a12y = p1y + (p2y - p1y) * t;
        float a23x = p2x + (p3x - p2x) * t, a23y = p2y + (p3y - p2y) * t;
        float qax = a01x + (a12x - a01x) * t, qay = a01y + (a12y - a01y) * t;
        float qbx = a12x + (a23x - a12x) * t, qby = a12y + (a23y - a12y) * t;
        xs[tid] = qax + (qbx - qax) * t;
        ys[tid] = qay + (qby - qay) * t;
    }
    __syncthreads();

    const int it = tid & 15, jt = tid >> 4;
    const int ib = it * 4, jb = jt * 4;    // 4x4 micro-tile origin in tile
    float acc[4][4];
#pragma unroll
    for (int r = 0; r < 4; ++r)
#pragma unroll
        for (int c = 0; c < 4; ++c) acc[r][c] = 0.0f;

    for (int chunk = 0; chunk < KB / KC; ++chunk) {
        // --- stage exp factor tiles: KC x TILE each, 256 threads ---
#pragma unroll
        for (int e = 0; e < (KC * TILE) / 256; ++e) {
            int idx = e * 256 + tid;
            int kk  = idx >> 6;            // TILE == 64
            int ii  = idx & 63;
            float xv = xs[chunk * KC + kk];     // wave-uniform -> LDS broadcast
            float yv = ys[chunk * KC + kk];
            float dx = xv - (float)(ibase + ii) * (1.0f / 512.0f);
            float dy = yv - (float)(jbase + ii) * (1.0f / 512.0f);
            ex_s[kk][ii] = __expf(dx * dx * (-5000.0f));
            ey_s[kk][ii] = __expf(dy * dy * (-5000.0f));
        }
        __syncthreads();

        // --- 4x4 outer-product accumulation over KC ---
#pragma unroll 4
        for (int kk = 0; kk < KC; ++kk) {
            const float4 a = *reinterpret_cast<const float4*>(&ex_s[kk][ib]);
            const float4 b = *reinterpret_cast<const float4*>(&ey_s[kk][jb]);
            acc[0][0] += b.x * a.x; acc[0][1] += b.x * a.y;
            acc[0][2] += b.x * a.z; acc[0][3] += b.x * a.w;
            acc[1][0] += b.y * a.x; acc[1][1] += b.y * a.y;
            acc[1][2] += b.y * a.z; acc[1][3] += b.y * a.w;
            acc[2][0] += b.z * a.x; acc[2][1] += b.z * a.y;
            acc[2][2] += b.z * a.z; acc[2][3] += b.z * a.w;
            acc[3][0] += b.w * a.x; acc[3][1] += b.w * a.y;
            acc[3][2] += b.w * a.z; acc[3][3] += b.w * a.w;
        }
        __syncthreads();
    }

    // --- combine K-slices: atomic add into zero-initialized output ---
#pragma unroll
    for (int r = 0; r < 4; ++r) {
        int j = jbase + jb + r;
#pragma unroll
        for (int c = 0; c < 4; ++c) {
            atomicAdd(&out[j * RES_ + ibase + ib + c], acc[r][c]);
        }
    }
}

extern "C" void kernel_launch(void* const* d_in, const int* in_sizes, int n_in,
                              void* d_out, int out_size, void* d_ws, size_t ws_size,
                              hipStream_t stream) {
    const float* curves = (const float*)d_in[0];
    float* out = (float*)d_out;

    // zero output (harness poisons with 0xAA); memsetAsync is graph-capturable
    hipMemsetAsync(out, 0, sizeof(float) * (size_t)out_size, stream);

    dim3 grid(RES_ / TILE, RES_ / TILE, 1024 / KB);  // (8, 8, 4) = 256 blocks
    bezier_raster<<<grid, dim3(256), 0, stream>>>(curves, out);
}

// Round 2
// 67.444 us; speedup vs baseline: 1.2774x; 1.2774x over previous
//
#include <hip/hip_runtime.h>

// out[j,i] = sum_k exp(-(x_k - i/512)^2 * 5000) * exp(-(y_k - j/512)^2 * 5000)
// 1024 points (8 curves x 128 steps), 512x512 fp32 output.
//
// Two kernels, no atomics:
//  K1: grid (8,8,8) -> 64x64 output tile x 128-wide K-slice; partial sums
//      stored to d_ws as plain float4 (8 x 1 MB partials).
//  K2: reduce 8 partials -> d_out (fully overwrites, no memset needed).

constexpr int RES_   = 512;
constexpr int TILE   = 64;   // output tile edge
constexpr int KSPLIT = 8;
constexpr int KB     = 1024 / KSPLIT;  // 128 K per block
constexpr int KC     = 64;             // K chunk staged in LDS

__global__ __launch_bounds__(256)
void bezier_partial(const float* __restrict__ curves, float* __restrict__ part) {
    __shared__ float xs[KB], ys[KB];
    __shared__ float ex_s[KC][TILE];   // 16 KB
    __shared__ float ey_s[KC][TILE];   // 16 KB

    const int tid   = threadIdx.x;
    const int ibase = blockIdx.x * TILE;   // output columns i
    const int jbase = blockIdx.y * TILE;   // output rows j
    const int kbase = blockIdx.z * KB;     // K slice

    // --- evaluate Bezier sample points (de Casteljau, fp32), threads 0..KB-1 ---
    if (tid < KB) {
        int p = kbase + tid;                       // global point index
        int c = p >> 7;                            // curve 0..7
        float t = (float)(p & 127) * (1.0f / 127.0f);
        const float* cp = curves + c * 8;          // 4 control points x (x,y)
        float p0x = cp[0], p0y = cp[1];
        float p1x = cp[2], p1y = cp[3];
        float p2x = cp[4], p2y = cp[5];
        float p3x = cp[6], p3y = cp[7];
        float a01x = p0x + (p1x - p0x) * t, a01y = p0y + (p1y - p0y) * t;
        float a12x = p1x + (p2x - p1x) * t, a12y = p1y + (p2y - p1y) * t;
        float a23x = p2x + (p3x - p2x) * t, a23y = p2y + (p3y - p2y) * t;
        float qax = a01x + (a12x - a01x) * t, qay = a01y + (a12y - a01y) * t;
        float qbx = a12x + (a23x - a12x) * t, qby = a12y + (a23y - a12y) * t;
        xs[tid] = qax + (qbx - qax) * t;
        ys[tid] = qay + (qby - qay) * t;
    }
    __syncthreads();

    const int it = tid & 15, jt = tid >> 4;
    const int ib = it * 4, jb = jt * 4;    // 4x4 micro-tile origin in tile
    float acc[4][4];
#pragma unroll
    for (int r = 0; r < 4; ++r)
#pragma unroll
        for (int c = 0; c < 4; ++c) acc[r][c] = 0.0f;

    for (int chunk = 0; chunk < KB / KC; ++chunk) {
        // --- stage exp factor tiles: KC x TILE each, 256 threads ---
#pragma unroll
        for (int e = 0; e < (KC * TILE) / 256; ++e) {
            int idx = e * 256 + tid;
            int kk  = idx >> 6;            // TILE == 64
            int ii  = idx & 63;
            float xv = xs[chunk * KC + kk];     // wave-uniform -> LDS broadcast
            float yv = ys[chunk * KC + kk];
            float dx = xv - (float)(ibase + ii) * (1.0f / 512.0f);
            float dy = yv - (float)(jbase + ii) * (1.0f / 512.0f);
            ex_s[kk][ii] = __expf(dx * dx * (-5000.0f));
            ey_s[kk][ii] = __expf(dy * dy * (-5000.0f));
        }
        __syncthreads();

        // --- 4x4 outer-product accumulation over KC ---
#pragma unroll 4
        for (int kk = 0; kk < KC; ++kk) {
            const float4 a = *reinterpret_cast<const float4*>(&ex_s[kk][ib]);
            const float4 b = *reinterpret_cast<const float4*>(&ey_s[kk][jb]);
            acc[0][0] += b.x * a.x; acc[0][1] += b.x * a.y;
            acc[0][2] += b.x * a.z; acc[0][3] += b.x * a.w;
            acc[1][0] += b.y * a.x; acc[1][1] += b.y * a.y;
            acc[1][2] += b.y * a.z; acc[1][3] += b.y * a.w;
            acc[2][0] += b.z * a.x; acc[2][1] += b.z * a.y;
            acc[2][2] += b.z * a.z; acc[2][3] += b.z * a.w;
            acc[3][0] += b.w * a.x; acc[3][1] += b.w * a.y;
            acc[3][2] += b.w * a.z; acc[3][3] += b.w * a.w;
        }
        __syncthreads();
    }

    // --- store partial tile: plain coalesced float4 stores, no atomics ---
    float* slice = part + (size_t)blockIdx.z * (RES_ * RES_);
#pragma unroll
    for (int r = 0; r < 4; ++r) {
        int j = jbase + jb + r;
        float4 v = make_float4(acc[r][0], acc[r][1], acc[r][2], acc[r][3]);
        *reinterpret_cast<float4*>(&slice[j * RES_ + ibase + ib]) = v;
    }
}

__global__ __launch_bounds__(256)
void reduce_k(const float* __restrict__ part, float* __restrict__ out) {
    int i = blockIdx.x * blockDim.x + threadIdx.x;   // float4 index, 65536 total
    const float4* p4 = reinterpret_cast<const float4*>(part);
    float4 s = p4[i];
#pragma unroll
    for (int z = 1; z < KSPLIT; ++z) {
        float4 v = p4[(size_t)z * (RES_ * RES_ / 4) + i];
        s.x += v.x; s.y += v.y; s.z += v.z; s.w += v.w;
    }
    reinterpret_cast<float4*>(out)[i] = s;
}

extern "C" void kernel_launch(void* const* d_in, const int* in_sizes, int n_in,
                              void* d_out, int out_size, void* d_ws, size_t ws_size,
                              hipStream_t stream) {
    const float* curves = (const float*)d_in[0];
    float* out  = (float*)d_out;
    float* part = (float*)d_ws;   // 8 MB of partials

    dim3 grid(RES_ / TILE, RES_ / TILE, KSPLIT);     // (8, 8, 8) = 512 blocks
    bezier_partial<<<grid, dim3(256), 0, stream>>>(curves, part);

    reduce_k<<<dim3(RES_ * RES_ / 4 / 256), dim3(256), 0, stream>>>(part, out);
}